// Round 8
// baseline (151.652 us; speedup 1.0000x reference)
//
#include <hip/hip_runtime.h>

#define NBATCH 16
#define MAXB 256
#define BS 16
#define HQ 32
#define HKV 8
#define G 4
#define HD 128
#define SCALE 0.08838834764831845f
#define NEGF -1.0e30f   // running-max init
#define NEGI -2.0e30f   // invalid-position score: exp(NEGI - m) == 0 for any m >= NEGF
#define RESCALE_THR 8.0f

// global -> LDS direct DMA, 16B per lane, dest = wave-uniform base + lane*16
typedef const __attribute__((address_space(1))) unsigned int* gas_t;
typedef __attribute__((address_space(3))) unsigned int* las_t;
#define GLDS(g, l) __builtin_amdgcn_global_load_lds((gas_t)(g), (las_t)(l), 16, 0, 0)

__device__ __forceinline__ float dot8(const float4 a0, const float4 a1,
                                      const float4 b0, const float4 b1) {
  return a0.x*b0.x + a0.y*b0.y + a0.z*b0.z + a0.w*b0.w +
         a1.x*b1.x + a1.y*b1.y + a1.z*b1.z + a1.w*b1.w;
}

// 16-lane DPP row reduction — pure VALU (DS-pipe shuffles were the r1-r4 limit)
template<int CTL>
__device__ __forceinline__ float dpp_row_add(float v) {
  const int s = __builtin_amdgcn_update_dpp(0, __float_as_int(v), CTL, 0xF, 0xF, true);
  return v + __int_as_float(s);
}
__device__ __forceinline__ float row_reduce_add(float v) {
  v = dpp_row_add<0x128>(v);  // row_ror:8
  v = dpp_row_add<0x124>(v);  // row_ror:4
  v = dpp_row_add<0x122>(v);  // row_ror:2
  v = dpp_row_add<0x121>(v);  // row_ror:1
  return v;                   // all 16 lanes of the row hold the sum
}

// Workgroup = (b, split): 512 threads = 8 waves, wave w = kv-head w.
// Cooperative LDS staging: a 4-position page = 16KB K + 16KB V, CONTIGUOUS in
// the [pos][head][dim] cache layout, DMA'd via global_load_lds (zero VGPR
// staging -> no spill, the r7 failure; contiguous 32KB streams -> fixes the
// 512B-granule fragmentation that capped r6 at 3.8 TB/s effective).
// Double-buffered in 64KB LDS (2 blocks/CU, 16 waves/CU); one __syncthreads
// per page (its vmcnt(0) drain is also the staging-arrival barrier).
// Lane mapping: tg = lane>>4 (position in page), tl = lane&15 owns dims
// {tl*4..tl*4+3, 64+tl*4..64+tl*4+3} -> consecutive-16B LDS reads (2-way
// bank aliasing = free). Last-token substitution happens in the staging
// source address (per-lane redirect to knew/vnew).
__global__ __launch_bounds__(512) void pa_split(
    const float* __restrict__ q,
    const float* __restrict__ knew,
    const float* __restrict__ vnew,
    const float* __restrict__ k_cache,
    const float* __restrict__ v_cache,
    const int* __restrict__ block_tables,
    const int* __restrict__ seq_lens,
    float* __restrict__ part_ml,   // [B][HKV][P][G][2]
    float* __restrict__ part_acc,  // [B][HKV][P][G][HD]
    int nsplit)
{
  __shared__ float lds[2][8192];   // per buffer: K = 4096 floats, V = 4096

  const int b     = blockIdx.x % NBATCH;   // batch-minor: balanced progress
  const int split = blockIdx.x / NBATCH;
  const int wv    = threadIdx.x >> 6;      // wave index = kv head
  const int lane  = threadIdx.x & 63;
  const int tg    = lane >> 4;
  const int tl    = lane & 15;

  const int seq_len = seq_lens[b];
  int per = (seq_len + nsplit - 1) / nsplit;
  per = (per + 15) & ~15;                  // 16-align: pages never straddle cache blocks
  const int s0 = split * per;
  const int s1 = min(seq_len, s0 + per);
  const int last = seq_len - 1;
  const size_t pidx = (size_t)(b*HKV + wv)*nsplit + split;

  if (s0 >= seq_len) {
    // inactive split: write a neutral partial (d_ws is not re-poisoned)
    if (tg == 0) {
      if (tl == 0) {
#pragma unroll
        for (int j = 0; j < G; ++j) {
          part_ml[(pidx*G + j)*2 + 0] = NEGF;
          part_ml[(pidx*G + j)*2 + 1] = 0.f;
        }
      }
      const float4 z = make_float4(0.f,0.f,0.f,0.f);
#pragma unroll
      for (int j = 0; j < G; ++j) {
        *(float4*)(part_acc + (pidx*G + j)*HD + tl*4)      = z;
        *(float4*)(part_acc + (pidx*G + j)*HD + 64 + tl*4) = z;
      }
    }
    return;
  }

  // q fragments in the chunked dim mapping
  float4 q0[G], q1[G];
#pragma unroll
  for (int j = 0; j < G; ++j) {
    const float* qp = q + (size_t)(b*HQ + wv*G + j)*HD;
    q0[j] = *(const float4*)(qp + tl*4);
    q1[j] = *(const float4*)(qp + 64 + tl*4);
  }

  float m[G], l[G];
  float4 a0[G], a1[G];
#pragma unroll
  for (int j = 0; j < G; ++j) {
    m[j] = NEGF; l[j] = 0.f;
    a0[j] = make_float4(0.f,0.f,0.f,0.f);
    a1[j] = make_float4(0.f,0.f,0.f,0.f);
  }

  const char* kcb = (const char*)k_cache;
  const char* vcb = (const char*)v_cache;
  const char* knb = (const char*)knew;
  const char* vnb = (const char*)vnew;
  const int btbase = b * MAXB;

  // stage one 4-position page (32KB) into buf; each wave DMAs 2KB K + 2KB V
  auto stage = [&](float* buf, const int p0) {
    const int blk = block_tables[btbase + (p0 >> 4)];
    const size_t pagebyte = ((size_t)blk*BS + (p0 & 15)) * (HKV*HD*4);
    char* dst = (char*)buf;
#pragma unroll
    for (int j = 0; j < 2; ++j) {
      const int off = j*8192 + wv*1024 + lane*16;  // byte offset in 16KB chunk
      const char* srcK = kcb + pagebyte + off;     // page rows are contiguous
      const char* srcV = vcb + pagebyte + off;
      if (p0 + (off >> 12) == last) {              // token written this step
        const int head = (off >> 9) & 7;
        const size_t noff = (size_t)(b*HKV + head)*512 + (off & 511);
        srcK = knb + noff;
        srcV = vnb + noff;
      }
      GLDS(srcK, dst + j*8192 + wv*1024);          // K half
      GLDS(srcV, dst + 16384 + j*8192 + wv*1024);  // V half
    }
  };

  // compute one staged page: position = tg, head = wv
  auto compute = [&](const float* buf, const int p0) {
    const int sv = p0 + tg;
    const bool valid = sv < s1;
    const float* Kb = buf + tg*1024 + wv*128;
    const float* Vb = Kb + 4096;
    const float4 k0 = *(const float4*)(Kb + tl*4);
    const float4 k1 = *(const float4*)(Kb + 64 + tl*4);
    const float4 v0 = *(const float4*)(Vb + tl*4);
    const float4 v1 = *(const float4*)(Vb + 64 + tl*4);

    float sc[G];
#pragma unroll
    for (int j = 0; j < G; ++j) {
      float p = dot8(q0[j], q1[j], k0, k1);
      p = row_reduce_add(p);
      sc[j] = valid ? p * SCALE : NEGI;
    }
    bool need = false;
#pragma unroll
    for (int j = 0; j < G; ++j) need = need || (sc[j] > m[j] + RESCALE_THR);
    if (__any(need)) {
#pragma unroll
      for (int j = 0; j < G; ++j) {
        const float mn = fmaxf(m[j], sc[j]);
        const float f  = __expf(m[j] - mn);
        l[j] *= f;
        a0[j].x *= f; a0[j].y *= f; a0[j].z *= f; a0[j].w *= f;
        a1[j].x *= f; a1[j].y *= f; a1[j].z *= f; a1[j].w *= f;
        m[j] = mn;
      }
    }
#pragma unroll
    for (int j = 0; j < G; ++j) {
      const float pp = __expf(sc[j] - m[j]);  // bounded by e^THR; 0 for invalid
      l[j] += pp;
      a0[j].x += pp*v0.x; a0[j].y += pp*v0.y; a0[j].z += pp*v0.z; a0[j].w += pp*v0.w;
      a1[j].x += pp*v1.x; a1[j].y += pp*v1.y; a1[j].z += pp*v1.z; a1[j].w += pp*v1.w;
    }
  };

  // ---- double-buffered page pipeline, one barrier per page ----
  stage(lds[0], s0);
  __syncthreads();                 // vmcnt(0) drain: page 0 arrived
  int cur = 0;
  for (int p0 = s0; p0 < s1; p0 += 4) {
    if (p0 + 4 < s1) stage(lds[cur ^ 1], p0 + 4);
    compute(lds[cur], p0);
    __syncthreads();               // next page arrived + cur free to overwrite
    cur ^= 1;
  }

  // combine the 4 tg partials (butterfly xor 16, 32) — once per wave
#pragma unroll
  for (int mask = 16; mask <= 32; mask <<= 1) {
#pragma unroll
    for (int j = 0; j < G; ++j) {
      const float mo = __shfl_xor(m[j], mask, 64);
      const float lo = __shfl_xor(l[j], mask, 64);
      const float mn = fmaxf(m[j], mo);
      const float f0 = __expf(m[j] - mn);
      const float f1 = __expf(mo  - mn);
      l[j] = l[j]*f0 + lo*f1;
      float t;
      t = __shfl_xor(a0[j].x, mask, 64); a0[j].x = a0[j].x*f0 + t*f1;
      t = __shfl_xor(a0[j].y, mask, 64); a0[j].y = a0[j].y*f0 + t*f1;
      t = __shfl_xor(a0[j].z, mask, 64); a0[j].z = a0[j].z*f0 + t*f1;
      t = __shfl_xor(a0[j].w, mask, 64); a0[j].w = a0[j].w*f0 + t*f1;
      t = __shfl_xor(a1[j].x, mask, 64); a1[j].x = a1[j].x*f0 + t*f1;
      t = __shfl_xor(a1[j].y, mask, 64); a1[j].y = a1[j].y*f0 + t*f1;
      t = __shfl_xor(a1[j].z, mask, 64); a1[j].z = a1[j].z*f0 + t*f1;
      t = __shfl_xor(a1[j].w, mask, 64); a1[j].w = a1[j].w*f0 + t*f1;
      m[j] = mn;
    }
  }

  if (tg == 0) {
    if (tl == 0) {
#pragma unroll
      for (int j = 0; j < G; ++j) {
        part_ml[(pidx*G + j)*2 + 0] = m[j];
        part_ml[(pidx*G + j)*2 + 1] = l[j];
      }
    }
#pragma unroll
    for (int j = 0; j < G; ++j) {
      *(float4*)(part_acc + (pidx*G + j)*HD + tl*4)      = a0[j];
      *(float4*)(part_acc + (pidx*G + j)*HD + 64 + tl*4) = a1[j];
    }
  }
}

// Reduce: one block per (b, q-head), 128 threads (one per dim).
__global__ __launch_bounds__(128) void pa_reduce(
    const float* __restrict__ part_ml,
    const float* __restrict__ part_acc,
    float* __restrict__ out,
    int P)
{
  const int qh = blockIdx.x % HQ;
  const int b  = blockIdx.x / HQ;
  const int h  = qh >> 2;
  const int j  = qh & 3;
  const int d  = threadIdx.x;

  const size_t base = (size_t)(b*HKV + h) * P;
  float mg = NEGF;
  for (int p = 0; p < P; ++p)
    mg = fmaxf(mg, part_ml[((base + p)*G + j)*2 + 0]);

  float lsum = 0.f, asum = 0.f;
  for (int p = 0; p < P; ++p) {
    const float mm = part_ml[((base + p)*G + j)*2 + 0];
    const float ll = part_ml[((base + p)*G + j)*2 + 1];
    const float f  = __expf(mm - mg);   // inactive partial: ll==0, acc==0
    lsum += f * ll;
    asum += f * part_acc[((base + p)*G + j)*HD + d];
  }
  out[(size_t)(b*HQ + qh)*HD + d] = asum / lsum;
}

extern "C" void kernel_launch(void* const* d_in, const int* in_sizes, int n_in,
                              void* d_out, int out_size, void* d_ws, size_t ws_size,
                              hipStream_t stream) {
  const float* q  = (const float*)d_in[0];
  const float* k  = (const float*)d_in[1];
  const float* v  = (const float*)d_in[2];
  const float* kc = (const float*)d_in[3];
  const float* vc = (const float*)d_in[4];
  // d_in[5] = slot_mapping (unused: it addresses logical position seq_len-1)
  const int* bt = (const int*)d_in[6];
  const int* sl = (const int*)d_in[7];
  // d_in[8] = query_lens (all 1), d_in[9] = is_prefill (False) — unused

  int nsplit = 64;
  for (;;) {
    const size_t need = (size_t)NBATCH * HKV * nsplit * G * (2 + HD) * sizeof(float);
    if (need <= ws_size || nsplit == 1) break;
    nsplit >>= 1;
  }
  float* part_ml  = (float*)d_ws;
  float* part_acc = part_ml + (size_t)NBATCH * HKV * nsplit * G * 2;

  hipLaunchKernelGGL(pa_split, dim3(NBATCH * nsplit), dim3(512), 0, stream,
                     q, k, v, kc, vc, bt, sl, part_ml, part_acc, nsplit);
  hipLaunchKernelGGL(pa_reduce, dim3(NBATCH * HQ), dim3(128), 0, stream,
                     part_ml, part_acc, (float*)d_out, nsplit);
}

// Round 9
// 105.452 us; speedup vs baseline: 1.4381x; 1.4381x over previous
//
#include <hip/hip_runtime.h>

#define NBATCH 16
#define MAXB 256
#define BS 16
#define HQ 32
#define HKV 8
#define G 4
#define HD 128
#define SCALE 0.08838834764831845f
#define NEGF -1.0e30f   // running-max init
#define NEGI -2.0e30f   // invalid-position score: exp(NEGI - m) == 0 for any m >= NEGF
#define RESCALE_THR 8.0f

__device__ __forceinline__ float dot8(const float4 a0, const float4 a1,
                                      const float4 b0, const float4 b1) {
  return a0.x*b0.x + a0.y*b0.y + a0.z*b0.z + a0.w*b0.w +
         a1.x*b1.x + a1.y*b1.y + a1.z*b1.z + a1.w*b1.w;
}

// 16-lane DPP row reduction — pure VALU (DS-pipe shuffles were the r1-r4 limit)
template<int CTL>
__device__ __forceinline__ float dpp_row_add(float v) {
  const int s = __builtin_amdgcn_update_dpp(0, __float_as_int(v), CTL, 0xF, 0xF, true);
  return v + __int_as_float(s);
}
__device__ __forceinline__ float row_reduce_add(float v) {
  v = dpp_row_add<0x128>(v);  // row_ror:8
  v = dpp_row_add<0x124>(v);  // row_ror:4
  v = dpp_row_add<0x122>(v);  // row_ror:2
  v = dpp_row_add<0x121>(v);  // row_ror:1
  return v;                   // all 16 lanes of the row hold the sum
}

// Workgroup = (b, split, hg): 256 threads = 4 waves, wave w = kv-head hg*4+w.
// Lanes: tg = lane>>4 (position within a 4-pos group), tl = lane&15 (dims
// [tl*8, tl*8+8)).
//
// r6 post-mortem: page loads issued as a 16-load burst collapse to ~4 loads
// in flight (register reuse forces serialization) -> ~4 latency round-trips
// per page -> 3.8 TB/s effective wall. Fix: modulo-scheduled rotating
// pipeline at 4-position granularity with 4 NAMED buffers (rule #20: static
// indexing only): compute(g) interleaved with load(g+4). Each compute
// depends only on loads issued 3 groups earlier -> steady ~12 loads/wave in
// flight, no burst-drain sawtooth. Staging drops 128->64 VGPRs -> ~155 live
// -> 3 waves/SIMD (12/CU), +50% TLP over r6. Block table prefetched 2 pages
// ahead (r8 lesson: keep it off the load critical path).
__global__ __launch_bounds__(256) void pa_split(
    const float* __restrict__ q,
    const float* __restrict__ knew,
    const float* __restrict__ vnew,
    const float* __restrict__ k_cache,
    const float* __restrict__ v_cache,
    const int* __restrict__ block_tables,
    const int* __restrict__ seq_lens,
    float* __restrict__ part_ml,   // [B][HKV][P][G][2]
    float* __restrict__ part_acc,  // [B][HKV][P][G][HD]
    int nsplit)
{
  const int hg    = blockIdx.x & 1;
  const int b     = (blockIdx.x >> 1) % NBATCH;    // batch-minor: balance
  const int split = blockIdx.x / (2 * NBATCH);
  const int h     = hg * 4 + (threadIdx.x >> 6);
  const int lane  = threadIdx.x & 63;
  const int tg    = lane >> 4;
  const int tl    = lane & 15;

  const int seq_len = seq_lens[b];
  int per = (seq_len + nsplit - 1) / nsplit;
  per = (per + 15) & ~15;                          // page-align chunks
  const int s0 = split * per;
  const int s1 = min(seq_len, s0 + per);
  const int last = seq_len - 1;
  const size_t pidx = (size_t)(b*HKV + h)*nsplit + split;

  if (s0 >= seq_len) {
    // inactive split: write a neutral partial (d_ws is not re-poisoned)
    if (tg == 0) {
      if (tl == 0) {
#pragma unroll
        for (int j = 0; j < G; ++j) {
          part_ml[(pidx*G + j)*2 + 0] = NEGF;
          part_ml[(pidx*G + j)*2 + 1] = 0.f;
        }
      }
      const float4 z = make_float4(0.f,0.f,0.f,0.f);
#pragma unroll
      for (int j = 0; j < G; ++j) {
        float4* ap = (float4*)(part_acc + (pidx*G + j)*HD + tl*8);
        ap[0] = z; ap[1] = z;
      }
    }
    return;
  }

  float4 q0[G], q1[G];
#pragma unroll
  for (int j = 0; j < G; ++j) {
    const float* qp = q + (size_t)(b*HQ + h*G + j)*HD + tl*8;
    q0[j] = ((const float4*)qp)[0];
    q1[j] = ((const float4*)qp)[1];
  }

  float m[G], l[G];
  float4 a0[G], a1[G];
#pragma unroll
  for (int j = 0; j < G; ++j) {
    m[j] = NEGF; l[j] = 0.f;
    a0[j] = make_float4(0.f,0.f,0.f,0.f);
    a1[j] = make_float4(0.f,0.f,0.f,0.f);
  }

  const float* knp = knew + (size_t)(b*HKV + h)*HD + tl*8;
  const float* vnp = vnew + (size_t)(b*HKV + h)*HD + tl*8;
  const int btbase = b * MAXB;

  // load one 4-position group: positions pos+tg (pos = multiple of 4 within
  // the page mapped by blk). Loading past s1 within a mapped page is safe.
  auto loadG = [&](float4 (&kr)[2], float4 (&vr)[2], const int blk, const int pos) {
    const int s = pos + tg;
    const size_t off = ((size_t)blk*BS + (s & 15))*(HKV*HD) + (size_t)h*HD + tl*8;
    const float* kp = k_cache + off;
    const float* vp = v_cache + off;
    if (s == last) { kp = knp; vp = vnp; }  // token written this step -> k/v inputs
    kr[0] = ((const float4*)kp)[0];
    kr[1] = ((const float4*)kp)[1];
    vr[0] = ((const float4*)vp)[0];
    vr[1] = ((const float4*)vp)[1];
  };

  auto computeG = [&](const float4 (&kr)[2], const float4 (&vr)[2], const int pos) {
    const bool valid = (pos + tg) < s1;
    float sc[G];
#pragma unroll
    for (int j = 0; j < G; ++j) {
      float p = dot8(q0[j], q1[j], kr[0], kr[1]);
      p = row_reduce_add(p);                  // VALU-only 16-lane reduce
      sc[j] = valid ? p * SCALE : NEGI;
    }
    bool need = false;
#pragma unroll
    for (int j = 0; j < G; ++j) need = need || (sc[j] > m[j] + RESCALE_THR);
    if (__any(need)) {
#pragma unroll
      for (int j = 0; j < G; ++j) {
        const float mn = fmaxf(m[j], sc[j]);
        const float f  = __expf(m[j] - mn);
        l[j] *= f;
        a0[j].x *= f; a0[j].y *= f; a0[j].z *= f; a0[j].w *= f;
        a1[j].x *= f; a1[j].y *= f; a1[j].z *= f; a1[j].w *= f;
        m[j] = mn;
      }
    }
#pragma unroll
    for (int j = 0; j < G; ++j) {
      const float pp = __expf(sc[j] - m[j]);  // bounded by e^THR; 0 for invalid
      l[j] += pp;
      a0[j].x += pp*vr[0].x; a0[j].y += pp*vr[0].y;
      a0[j].z += pp*vr[0].z; a0[j].w += pp*vr[0].w;
      a1[j].x += pp*vr[1].x; a1[j].y += pp*vr[1].y;
      a1[j].z += pp*vr[1].z; a1[j].w += pp*vr[1].w;
    }
  };

  // ---- rotating 4-buffer pipeline: compute(g) || load(g+4) ----
  const int npos   = s1 - s0;
  const int npages = (npos + 15) >> 4;
  const int pg0    = s0 >> 4;

  float4 kA[2], vA[2], kB[2], vB[2], kC[2], vC[2], kD[2], vD[2];

  int blkCur  = block_tables[btbase + pg0];
  int blkNext = block_tables[btbase + pg0 + ((npages > 1) ? 1 : 0)];

  loadG(kA, vA, blkCur, s0);
  loadG(kB, vB, blkCur, s0 + 4);
  loadG(kC, vC, blkCur, s0 + 8);
  loadG(kD, vD, blkCur, s0 + 12);

  for (int p = 0; p < npages; ++p) {
    const int base  = s0 + p*16;
    const bool more = (p + 1 < npages);
    const int blkL  = blkNext;
    const int lbase = base + 16;
    // prefetch block index for page p+2 (clamped; off the critical path)
    const int pnn   = (p + 2 < npages) ? (p + 2) : (npages - 1);
    const int blkNN = block_tables[btbase + pg0 + pnn];

    computeG(kA, vA, base);
    if (more) loadG(kA, vA, blkL, lbase);
    computeG(kB, vB, base + 4);
    if (more) loadG(kB, vB, blkL, lbase + 4);
    computeG(kC, vC, base + 8);
    if (more) loadG(kC, vC, blkL, lbase + 8);
    computeG(kD, vD, base + 12);
    if (more) loadG(kD, vD, blkL, lbase + 12);

    blkNext = blkNN;
  }

  // combine the 4 tg partials (butterfly xor 16, 32) — once per wave.
  // Never-valid rows carry m=NEGF, l=0 -> weight 0.
#pragma unroll
  for (int mask = 16; mask <= 32; mask <<= 1) {
#pragma unroll
    for (int j = 0; j < G; ++j) {
      const float mo = __shfl_xor(m[j], mask, 64);
      const float lo = __shfl_xor(l[j], mask, 64);
      const float mn = fmaxf(m[j], mo);
      const float f0 = __expf(m[j] - mn);
      const float f1 = __expf(mo  - mn);
      l[j] = l[j]*f0 + lo*f1;
      float t;
      t = __shfl_xor(a0[j].x, mask, 64); a0[j].x = a0[j].x*f0 + t*f1;
      t = __shfl_xor(a0[j].y, mask, 64); a0[j].y = a0[j].y*f0 + t*f1;
      t = __shfl_xor(a0[j].z, mask, 64); a0[j].z = a0[j].z*f0 + t*f1;
      t = __shfl_xor(a0[j].w, mask, 64); a0[j].w = a0[j].w*f0 + t*f1;
      t = __shfl_xor(a1[j].x, mask, 64); a1[j].x = a1[j].x*f0 + t*f1;
      t = __shfl_xor(a1[j].y, mask, 64); a1[j].y = a1[j].y*f0 + t*f1;
      t = __shfl_xor(a1[j].z, mask, 64); a1[j].z = a1[j].z*f0 + t*f1;
      t = __shfl_xor(a1[j].w, mask, 64); a1[j].w = a1[j].w*f0 + t*f1;
      m[j] = mn;
    }
  }

  if (tg == 0) {
    if (tl == 0) {
#pragma unroll
      for (int j = 0; j < G; ++j) {
        part_ml[(pidx*G + j)*2 + 0] = m[j];
        part_ml[(pidx*G + j)*2 + 1] = l[j];
      }
    }
#pragma unroll
    for (int j = 0; j < G; ++j) {
      float4* ap = (float4*)(part_acc + (pidx*G + j)*HD + tl*8);
      ap[0] = a0[j];
      ap[1] = a1[j];
    }
  }
}

// Reduce: one block per (b, q-head), 128 threads (one per dim).
__global__ __launch_bounds__(128) void pa_reduce(
    const float* __restrict__ part_ml,
    const float* __restrict__ part_acc,
    float* __restrict__ out,
    int P)
{
  const int qh = blockIdx.x % HQ;
  const int b  = blockIdx.x / HQ;
  const int h  = qh >> 2;
  const int j  = qh & 3;
  const int d  = threadIdx.x;

  const size_t base = (size_t)(b*HKV + h) * P;
  float mg = NEGF;
  for (int p = 0; p < P; ++p)
    mg = fmaxf(mg, part_ml[((base + p)*G + j)*2 + 0]);

  float lsum = 0.f, asum = 0.f;
  for (int p = 0; p < P; ++p) {
    const float mm = part_ml[((base + p)*G + j)*2 + 0];
    const float ll = part_ml[((base + p)*G + j)*2 + 1];
    const float f  = __expf(mm - mg);   // inactive partial: ll==0, acc==0
    lsum += f * ll;
    asum += f * part_acc[((base + p)*G + j)*HD + d];
  }
  out[(size_t)(b*HQ + qh)*HD + d] = asum / lsum;
}

extern "C" void kernel_launch(void* const* d_in, const int* in_sizes, int n_in,
                              void* d_out, int out_size, void* d_ws, size_t ws_size,
                              hipStream_t stream) {
  const float* q  = (const float*)d_in[0];
  const float* k  = (const float*)d_in[1];
  const float* v  = (const float*)d_in[2];
  const float* kc = (const float*)d_in[3];
  const float* vc = (const float*)d_in[4];
  // d_in[5] = slot_mapping (unused: it addresses logical position seq_len-1)
  const int* bt = (const int*)d_in[6];
  const int* sl = (const int*)d_in[7];
  // d_in[8] = query_lens (all 1), d_in[9] = is_prefill (False) — unused

  int nsplit = 32;
  for (;;) {
    const size_t need = (size_t)NBATCH * HKV * nsplit * G * (2 + HD) * sizeof(float);
    if (need <= ws_size || nsplit == 1) break;
    nsplit >>= 1;
  }
  float* part_ml  = (float*)d_ws;
  float* part_acc = part_ml + (size_t)NBATCH * HKV * nsplit * G * 2;

  hipLaunchKernelGGL(pa_split, dim3(NBATCH * nsplit * 2), dim3(256), 0, stream,
                     q, k, v, kc, vc, bt, sl, part_ml, part_acc, nsplit);
  hipLaunchKernelGGL(pa_reduce, dim3(NBATCH * HQ), dim3(128), 0, stream,
                     part_ml, part_acc, (float*)d_out, nsplit);
}